// Round 2
// baseline (644.462 us; speedup 1.0000x reference)
//
#include <hip/hip_runtime.h>
#include <hip/hip_bf16.h>
#include <cstdint>
#include <cstddef>

typedef __attribute__((ext_vector_type(8))) short short8;
typedef __attribute__((ext_vector_type(4))) float floatx4;

#define MFMA_BF16(a,b,c) __builtin_amdgcn_mfma_f32_16x16x32_bf16((a),(b),(c),0,0,0)

__device__ __forceinline__ float bf2f(short s) {
    return __uint_as_float(((unsigned int)(unsigned short)s) << 16);
}
__device__ __forceinline__ unsigned short f2bf(float f) {
    unsigned int u = __float_as_uint(f);
    u += 0x7FFFu + ((u >> 16) & 1u);
    return (unsigned short)(u >> 16);
}
__device__ __forceinline__ int bucketd(int d) {
    if (d < 0) d = 0;
    if (d <= 4) return d;
    int b = 34 - __clz(d);          // floor(log2(d)) + 3
    return b > 9 ? 9 : b;
}

// ---------------- init: small precomputes ----------------
__global__ void k_init(const float* __restrict__ span_vecs, const float* __restrict__ span_scores,
                       const float* __restrict__ W1g, const float* __restrict__ Edist,
                       const float* __restrict__ Wd, const float* __restrict__ bd,
                       const float* __restrict__ b1, const float* __restrict__ Wo,
                       const float* __restrict__ bl, const float* __restrict__ br, const float* __restrict__ bp,
                       float* __restrict__ updatef, unsigned short* __restrict__ ubf0,
                       float* __restrict__ ssbuf,
                       unsigned short* __restrict__ W1T, unsigned short* __restrict__ Pb,
                       float* __restrict__ b1p, float* __restrict__ wop,
                       float* __restrict__ bproj, unsigned short* __restrict__ WprojT)
{
    int gsz = gridDim.x * blockDim.x;
    int g = blockIdx.x * blockDim.x + threadIdx.x;
    for (int i = g; i < 512*1024; i += gsz) {
        float v = span_vecs[i];
        updatef[i] = v;
        int r = i >> 10, c = i & 1023;
        ubf0[r*2048 + c] = f2bf(v);
    }
    for (int i = g; i < 512; i += gsz) ssbuf[i] = span_scores[i];
    // W1T [160][168] = W1[k][n] transposed+padded
    for (int i = g; i < 160*168; i += gsz) {
        int n = i / 168, k = i % 168;
        float v = (n < 150 && k < 150) ? W1g[k*150 + n] : 0.f;
        W1T[i] = f2bf(v);
    }
    // Pb [10][168] = Edist@Wd + bd
    for (int i = g; i < 10*168; i += gsz) {
        int b = i / 168, h = i % 168;
        float v = 0.f;
        if (h < 150) {
            v = bd[h];
            for (int e = 0; e < 20; ++e) v += Edist[b*20 + e] * Wd[e*150 + h];
        }
        Pb[i] = f2bf(v);
    }
    for (int i = g; i < 160; i += gsz) {
        b1p[i] = (i < 150) ? b1[i] : 0.f;
        wop[i] = (i < 150) ? Wo[i] : 0.f;
    }
    for (int i = g; i < 576; i += gsz) {
        float v = 0.f;
        if (i < 150) v = bl[i];
        else if (i >= 192 && i < 342) v = br[i - 192];
        else if (i >= 384 && i < 534) v = bp[i - 384];
        bproj[i] = v;
    }
    for (int i = g; i < 576*1024; i += gsz) WprojT[i] = 0;
}

// ---------------- transpose fp32 [R][C] -> bf16 out[c*ldo + r] ----------------
__global__ __launch_bounds__(256) void k_transpose(const float* __restrict__ in,
                                                   unsigned short* __restrict__ out,
                                                   int R, int C, int ldo)
{
    __shared__ float tile[32][33];
    int tx = threadIdx.x & 31, ty = threadIdx.x >> 5;
    int rb = blockIdx.x * 32, cb = blockIdx.y * 32;
#pragma unroll
    for (int k = 0; k < 4; ++k) {
        int r = rb + ty + k*8, c = cb + tx;
        if (r < R && c < C) tile[ty + k*8][tx] = in[(size_t)r*C + c];
    }
    __syncthreads();
#pragma unroll
    for (int k = 0; k < 4; ++k) {
        int c = cb + ty + k*8, r = rb + tx;
        if (r < R && c < C) out[(size_t)c*ldo + r] = f2bf(tile[tx][ty + k*8]);
    }
}

// ---------------- generic 64x64 bf16 MFMA GEMM, fused epilogues ----------------
// C[m][n] = sum_k A[m][k] * BT[n][k]
// mode 0: Cb = bf16(acc + bias)            (projections -> lrsb)
// mode 1: Cf = acc; Cb = bf16(acc)         (ctxt -> ctxtf + ubf second half)
// mode 2: g = sigmoid(acc+bias); nu = g*uf + (1-g)*cf; uout = nu; Cb = bf16(nu)
__global__ __launch_bounds__(256) void k_gemm64(
    const unsigned short* __restrict__ A, int lda,
    const unsigned short* __restrict__ BT, int ldb,
    int K, const float* __restrict__ bias,
    float* __restrict__ Cf, int ldc,
    unsigned short* __restrict__ Cb, int ldcb,
    const float* __restrict__ uf, const float* __restrict__ cf,
    float* __restrict__ uout, int mode)
{
    __shared__ __align__(16) unsigned short As[64*72];
    __shared__ __align__(16) unsigned short Bs[64*72];
    int tid = threadIdx.x;
    int lane = tid & 63, w = tid >> 6;
    int wy = w >> 1, wx = w & 1;
    int ln15 = lane & 15, kg = lane >> 4;
    int m0 = blockIdx.x * 64, n0 = blockIdx.y * 64;
    floatx4 acc[2][2] = {};
    for (int kb = 0; kb < K; kb += 64) {
#pragma unroll
        for (int s = 0; s < 2; ++s) {
            int idx = tid + s*256;
            int r = idx >> 3, c8 = (idx & 7) * 8;
            *(uint4*)(&As[r*72 + c8]) = *(const uint4*)(A + (size_t)(m0 + r)*lda + kb + c8);
            *(uint4*)(&Bs[r*72 + c8]) = *(const uint4*)(BT + (size_t)(n0 + r)*ldb + kb + c8);
        }
        __syncthreads();
#pragma unroll
        for (int ks = 0; ks < 2; ++ks) {
            int ko = ks*32 + kg*8;
            short8 a0 = *(const short8*)(&As[(wy*32 + ln15)*72 + ko]);
            short8 a1 = *(const short8*)(&As[(wy*32 + 16 + ln15)*72 + ko]);
            short8 b0 = *(const short8*)(&Bs[(wx*32 + ln15)*72 + ko]);
            short8 b1 = *(const short8*)(&Bs[(wx*32 + 16 + ln15)*72 + ko]);
            acc[0][0] = MFMA_BF16(a0, b0, acc[0][0]);
            acc[0][1] = MFMA_BF16(a0, b1, acc[0][1]);
            acc[1][0] = MFMA_BF16(a1, b0, acc[1][0]);
            acc[1][1] = MFMA_BF16(a1, b1, acc[1][1]);
        }
        __syncthreads();
    }
#pragma unroll
    for (int mt = 0; mt < 2; ++mt)
#pragma unroll
    for (int nt = 0; nt < 2; ++nt)
#pragma unroll
    for (int rg = 0; rg < 4; ++rg) {
        int m = m0 + wy*32 + mt*16 + kg*4 + rg;
        int n = n0 + wx*32 + nt*16 + ln15;
        float v = acc[mt][nt][rg];
        if (mode == 0) {
            v += bias[n];
            Cb[(size_t)m*ldcb + n] = f2bf(v);
        } else if (mode == 1) {
            Cf[(size_t)m*ldc + n] = v;
            Cb[(size_t)m*ldcb + n] = f2bf(v);
        } else {
            v += bias[n];
            float gg = 1.f / (1.f + __expf(-v));
            float u = uf[(size_t)m*1024 + n];
            float c = cf[(size_t)m*1024 + n];
            float nu = gg*u + (1.f - gg)*c;
            uout[(size_t)m*1024 + n] = nu;
            Cb[(size_t)m*ldcb + n] = f2bf(nu);
        }
    }
}

// ---------------- row softmax (masked j<=i) -> bf16 probs ----------------
__global__ __launch_bounds__(256) void k_softmax(const float* __restrict__ scores,
                                                 unsigned short* __restrict__ probsb)
{
    int i = blockIdx.x;
    int tid = threadIdx.x;
    int lane = tid & 63, w = tid >> 6;
    __shared__ float red[8];
    int j0 = tid, j1 = tid + 256;
    bool v0 = (j0 <= i), v1 = (j1 <= i);
    float x0 = v0 ? scores[(size_t)i*512 + j0] : -1e30f;
    float x1 = v1 ? scores[(size_t)i*512 + j1] : -1e30f;
    float mx = fmaxf(x0, x1);
    for (int off = 32; off; off >>= 1) mx = fmaxf(mx, __shfl_xor(mx, off));
    if (lane == 0) red[w] = mx;
    __syncthreads();
    mx = fmaxf(fmaxf(red[0], red[1]), fmaxf(red[2], red[3]));
    float p0 = v0 ? __expf(x0 - mx) : 0.f;
    float p1 = v1 ? __expf(x1 - mx) : 0.f;
    float sm = p0 + p1;
    for (int off = 32; off; off >>= 1) sm += __shfl_xor(sm, off);
    if (lane == 0) red[4 + w] = sm;
    __syncthreads();
    float inv = 1.f / (red[4] + red[5] + red[6] + red[7]);
    probsb[(size_t)i*512 + j0] = f2bf(p0 * inv);
    probsb[(size_t)i*512 + j1] = f2bf(p1 * inv);
}

// ---------------- pruner: ss[i] = update[i] . Wpr + bpr ----------------
__global__ __launch_bounds__(256) void k_pruner(const float* __restrict__ updatef,
                                                const float* __restrict__ Wpr,
                                                const float* __restrict__ bpr,
                                                float* __restrict__ ssbuf)
{
    int w = (blockIdx.x * blockDim.x + threadIdx.x) >> 6;
    int lane = threadIdx.x & 63;
    if (w >= 512) return;
    const float4* ur = (const float4*)(updatef + (size_t)w*1024);
    const float4* wr = (const float4*)Wpr;
    float s = 0.f;
#pragma unroll
    for (int it = 0; it < 4; ++it) {
        int idx = lane + it*64;
        float4 a = ur[idx], b = wr[idx];
        s += a.x*b.x + a.y*b.y + a.z*b.z + a.w*b.w;
    }
    for (int off = 32; off; off >>= 1) s += __shfl_xor(s, off);
    if (lane == 0) ssbuf[w] = s + bpr[0];
}

// ---------------- pair kernel: fused h -> h@W1 -> relu -> .Wo -> scores ----------------
// block = 16 i's x 16 j's = 256 pairs, 512 threads (8 waves, 2 M-tiles each)
__global__ __launch_bounds__(512, 2) void k_pair(
    const unsigned short* __restrict__ lrsb,   // [512][576] bf16: l|pad|r|pad|s|pad
    const unsigned short* __restrict__ Pb,     // [10][168]
    const unsigned short* __restrict__ W1Tg,   // [160][168]
    const float* __restrict__ b1p, const float* __restrict__ wop,
    const float* __restrict__ bo,
    const float* __restrict__ ssbuf,
    const int* __restrict__ beginp, const int* __restrict__ endp,
    float* __restrict__ scoresOut)
{
    __shared__ __align__(16) unsigned short smR[74*168]; // l_i(16) s_i(16) r_j(16) s_j(16) P(10)
    __shared__ __align__(16) unsigned short smB[160*40]; // W1T k-slice
    int tid = threadIdx.x;
    int i0 = blockIdx.x * 16, j0 = blockIdx.y * 16;
    for (int c = tid; c < 74*21; c += 512) {
        int row = c / 21, c8 = (c % 21) * 8;
        const unsigned short* src;
        if (row < 16)      src = lrsb + (size_t)(i0 + row)*576 + c8;          // l_i
        else if (row < 32) src = lrsb + (size_t)(i0 + row - 16)*576 + 384 + c8; // s_i
        else if (row < 48) src = lrsb + (size_t)(j0 + row - 32)*576 + 192 + c8; // r_j
        else if (row < 64) src = lrsb + (size_t)(j0 + row - 48)*576 + 384 + c8; // s_j
        else               src = Pb + (size_t)(row - 64)*168 + c8;              // P
        *(uint4*)(&smR[row*168 + c8]) = *(const uint4*)src;
    }
    int lane = tid & 63, w = tid >> 6;
    int ln15 = lane & 15, kg = lane >> 4;
    int iw = i0 + 2*w;
    int j = j0 + ln15;
    int ej = endp[j];
    int da = bucketd(beginp[iw] - ej);
    int db = bucketd(beginp[iw + 1] - ej);
    floatx4 acc[2][10] = {};
    for (int kb = 0; kb < 5; ++kb) {
        __syncthreads();
        for (int c = tid; c < 160*4; c += 512) {
            int n = c >> 2, c8 = (c & 3) * 8;
            *(uint4*)(&smB[n*40 + c8]) = *(const uint4*)(W1Tg + (size_t)n*168 + kb*32 + c8);
        }
        __syncthreads();
        int ko = kb*32 + kg*8;
        short8 rv  = *(const short8*)(&smR[(32 + ln15)*168 + ko]);
        short8 sjv = *(const short8*)(&smR[(48 + ln15)*168 + ko]);
        short8 hf[2];
#pragma unroll
        for (int mt = 0; mt < 2; ++mt) {
            int ri = 2*w + mt;
            short8 lv  = *(const short8*)(&smR[ri*168 + ko]);
            short8 siv = *(const short8*)(&smR[(16 + ri)*168 + ko]);
            int d = mt ? db : da;
            short8 pv  = *(const short8*)(&smR[(64 + d)*168 + ko]);
#pragma unroll
            for (int t = 0; t < 8; ++t) {
                float h = bf2f(lv[t]) + bf2f(rv[t]) + bf2f(siv[t]) * bf2f(sjv[t]) + bf2f(pv[t]);
                h = fmaxf(h, 0.f);
                hf[mt][t] = (short)f2bf(h);
            }
        }
#pragma unroll
        for (int nt = 0; nt < 10; ++nt) {
            short8 bv = *(const short8*)(&smB[(nt*16 + ln15)*40 + kg*8]);
            acc[0][nt] = MFMA_BF16(hf[0], bv, acc[0][nt]);
            acc[1][nt] = MFMA_BF16(hf[1], bv, acc[1][nt]);
        }
    }
    // epilogue: h1 = relu(acc + b1), score_part = h1 . Wo
    float part[2][4] = {};
#pragma unroll
    for (int nt = 0; nt < 10; ++nt) {
        int n = nt*16 + ln15;
        float b1v = b1p[n], wv = wop[n];
#pragma unroll
        for (int mt = 0; mt < 2; ++mt)
#pragma unroll
            for (int rg = 0; rg < 4; ++rg)
                part[mt][rg] += fmaxf(acc[mt][nt][rg] + b1v, 0.f) * wv;
    }
    float bo0 = bo[0];
#pragma unroll
    for (int mt = 0; mt < 2; ++mt) {
#pragma unroll
        for (int rg = 0; rg < 4; ++rg) {
            float p = part[mt][rg];
            p += __shfl_xor(p, 1); p += __shfl_xor(p, 2);
            p += __shfl_xor(p, 4); p += __shfl_xor(p, 8);
            part[mt][rg] = p;
        }
        if (ln15 == 0) {
            int i = iw + mt;
            float ssi = ssbuf[i];
            int jb = j0 + kg*4;
            float r0 = part[mt][0] + bo0 + ssi + ssbuf[jb + 0]; if (i == jb + 0) r0 = 0.f;
            float r1 = part[mt][1] + bo0 + ssi + ssbuf[jb + 1]; if (i == jb + 1) r1 = 0.f;
            float r2 = part[mt][2] + bo0 + ssi + ssbuf[jb + 2]; if (i == jb + 2) r2 = 0.f;
            float r3 = part[mt][3] + bo0 + ssi + ssbuf[jb + 3]; if (i == jb + 3) r3 = 0.f;
            float4 vv; vv.x = r0; vv.y = r1; vv.z = r2; vv.w = r3;
            *(float4*)(scoresOut + (size_t)i*512 + jb) = vv;
        }
    }
}

// ---------------- finalize ----------------
__global__ void k_finalcopy(const float4* __restrict__ allv, const float4* __restrict__ updatef,
                            float4* __restrict__ out)
{
    const int NA = 31457280/4, NU = 524288/4;
    int gsz = gridDim.x * blockDim.x;
    for (int i = blockIdx.x*blockDim.x + threadIdx.x; i < NA + NU; i += gsz)
        out[i] = (i < NA) ? allv[i] : updatef[i - NA];
}

// prune_indices arrive as int32 (harness delivers all integer inputs as int32)
__global__ void k_overwrite(const int* __restrict__ prune, const int* __restrict__ lengths,
                            const float* __restrict__ updatef, float* __restrict__ out)
{
    int k = blockIdx.x;
    if (k >= lengths[0]) return;
    int row = prune[k];
    if (row < 0 || row >= 30720) return;   // defensive: never write OOB
    const float4* src = (const float4*)(updatef + (size_t)k*1024);
    float4* dst = (float4*)(out + (size_t)row*1024);
    dst[threadIdx.x] = src[threadIdx.x];
}

// ---------------- host ----------------
extern "C" void kernel_launch(void* const* d_in, const int* in_sizes, int n_in,
                              void* d_out, int out_size, void* d_ws, size_t ws_size,
                              hipStream_t stream) {
    const float* all_span    = (const float*)d_in[0];
    const float* span_vecs   = (const float*)d_in[1];
    const float* span_scores = (const float*)d_in[2];
    const int*   beginp      = (const int*)d_in[4];
    const int*   endp        = (const int*)d_in[5];
    const int*   prune       = (const int*)d_in[6];
    const int*   lengths     = (const int*)d_in[7];
    const float* Wl = (const float*)d_in[8];  const float* bl = (const float*)d_in[9];
    const float* Wr = (const float*)d_in[10]; const float* br = (const float*)d_in[11];
    const float* Wp = (const float*)d_in[12]; const float* bp = (const float*)d_in[13];
    const float* Edist = (const float*)d_in[14];
    const float* Wd = (const float*)d_in[15]; const float* bd = (const float*)d_in[16];
    const float* W1 = (const float*)d_in[17]; const float* b1 = (const float*)d_in[18];
    const float* Wo = (const float*)d_in[19]; const float* bo = (const float*)d_in[20];
    const float* Wg = (const float*)d_in[21]; const float* bg = (const float*)d_in[22];
    const float* Wpr = (const float*)d_in[23]; const float* bpr = (const float*)d_in[24];

    char* wsb = (char*)d_ws;
    size_t o = 0;
    auto nxt = [&](size_t b) { size_t r = o; o += (b + 255) & ~(size_t)255; return r; };
    float* updatef  = (float*)(wsb + nxt(512*1024*4));
    float* ctxtf    = (float*)(wsb + nxt(512*1024*4));
    float* scoresws = (float*)(wsb + nxt(512*512*4));
    float* ssbuf    = (float*)(wsb + nxt(512*4));
    float* bproj    = (float*)(wsb + nxt(576*4));
    float* b1p      = (float*)(wsb + nxt(160*4));
    float* wop      = (float*)(wsb + nxt(160*4));
    unsigned short* ubf0    = (unsigned short*)(wsb + nxt(512*2048*2));
    unsigned short* ubf1    = (unsigned short*)(wsb + nxt(512*2048*2));
    unsigned short* updT    = (unsigned short*)(wsb + nxt(1024*512*2));
    unsigned short* probsb  = (unsigned short*)(wsb + nxt(512*512*2));
    unsigned short* lrsb    = (unsigned short*)(wsb + nxt(512*576*2));
    unsigned short* WgT     = (unsigned short*)(wsb + nxt(1024*2048*2));
    unsigned short* WprojT  = (unsigned short*)(wsb + nxt(576*1024*2));
    unsigned short* W1T     = (unsigned short*)(wsb + nxt(160*168*2));
    unsigned short* Pb      = (unsigned short*)(wsb + nxt(10*168*2));

    float* outp = (float*)d_out;
    float* out_scores = outp + 31457280 + 524288;

    k_init<<<1024, 256, 0, stream>>>(span_vecs, span_scores, W1, Edist, Wd, bd, b1, Wo, bl, br, bp,
                                     updatef, ubf0, ssbuf, W1T, Pb, b1p, wop, bproj, WprojT);
    k_transpose<<<dim3(64, 32), 256, 0, stream>>>(Wg, WgT, 2048, 1024, 2048);
    k_transpose<<<dim3(32, 5), 256, 0, stream>>>(Wl, WprojT, 1024, 150, 1024);
    k_transpose<<<dim3(32, 5), 256, 0, stream>>>(Wr, WprojT + 192*1024, 1024, 150, 1024);
    k_transpose<<<dim3(32, 5), 256, 0, stream>>>(Wp, WprojT + 384*1024, 1024, 150, 1024);

    // call 0: projections from span_vecs, pair scores with span_scores
    k_gemm64<<<dim3(8, 9), 256, 0, stream>>>(ubf0, 2048, WprojT, 1024, 1024, bproj,
                                             nullptr, 0, lrsb, 576, nullptr, nullptr, nullptr, 0);
    k_pair<<<dim3(32, 32), 512, 0, stream>>>(lrsb, Pb, W1T, b1p, wop, bo, ssbuf, beginp, endp, scoresws);

    unsigned short* ucur = ubf0;
    unsigned short* unxt = ubf1;
    for (int it = 0; it < 2; ++it) {
        k_softmax<<<512, 256, 0, stream>>>(scoresws, probsb);
        k_transpose<<<dim3(16, 32), 256, 0, stream>>>(updatef, updT, 512, 1024, 512);
        k_gemm64<<<dim3(8, 16), 256, 0, stream>>>(probsb, 512, updT, 512, 512, nullptr,
                                                  ctxtf, 1024, ucur + 1024, 2048,
                                                  nullptr, nullptr, nullptr, 1);
        k_gemm64<<<dim3(8, 16), 256, 0, stream>>>(ucur, 2048, WgT, 2048, 2048, bg,
                                                  nullptr, 0, unxt, 2048,
                                                  updatef, ctxtf, updatef, 2);
        k_pruner<<<128, 256, 0, stream>>>(updatef, Wpr, bpr, ssbuf);
        k_gemm64<<<dim3(8, 9), 256, 0, stream>>>(unxt, 2048, WprojT, 1024, 1024, bproj,
                                                 nullptr, 0, lrsb, 576, nullptr, nullptr, nullptr, 0);
        float* sdst = (it == 1) ? out_scores : scoresws;
        k_pair<<<dim3(32, 32), 512, 0, stream>>>(lrsb, Pb, W1T, b1p, wop, bo, ssbuf, beginp, endp, sdst);
        unsigned short* t = ucur; ucur = unxt; unxt = t;
    }

    k_finalcopy<<<4096, 256, 0, stream>>>((const float4*)all_span, (const float4*)updatef, (float4*)d_out);
    k_overwrite<<<512, 256, 0, stream>>>(prune, lengths, updatef, outp);
}

// Round 3
// 514.925 us; speedup vs baseline: 1.2516x; 1.2516x over previous
//
#include <hip/hip_runtime.h>
#include <hip/hip_bf16.h>
#include <cstdint>
#include <cstddef>

typedef __attribute__((ext_vector_type(8))) short short8;
typedef __attribute__((ext_vector_type(4))) float floatx4;

#define MFMA_BF16(a,b,c) __builtin_amdgcn_mfma_f32_16x16x32_bf16((a),(b),(c),0,0,0)

__device__ __forceinline__ float bf2f(short s) {
    return __uint_as_float(((unsigned int)(unsigned short)s) << 16);
}
__device__ __forceinline__ unsigned short f2bf(float f) {
    unsigned int u = __float_as_uint(f);
    u += 0x7FFFu + ((u >> 16) & 1u);
    return (unsigned short)(u >> 16);
}
__device__ __forceinline__ int bucketd(int d) {
    if (d < 0) d = 0;
    if (d <= 4) return d;
    int b = 34 - __clz(d);          // floor(log2(d)) + 3
    return b > 9 ? 9 : b;
}

// ---------------- prep: all precomputes + weight transposes in ONE kernel ----------------
// blocks [0,2048): Wg transpose -> WgT[1024][2048]
// blocks [2048,2208): Wl -> WprojT rows 0..149
// blocks [2208,2368): Wr -> WprojT rows 192..341
// blocks [2368,2528): Wp -> WprojT rows 384..533
// blocks [2528,3040): span_vecs transpose -> updT[1024][512]
// blocks [3040,3552): misc init (grid-stride)
__global__ __launch_bounds__(256) void k_prep(
    const float* __restrict__ Wg, const float* __restrict__ Wl, const float* __restrict__ Wr,
    const float* __restrict__ Wp, const float* __restrict__ Wpr,
    const float* __restrict__ span_vecs, const float* __restrict__ span_scores,
    const float* __restrict__ W1g, const float* __restrict__ Edist,
    const float* __restrict__ Wd, const float* __restrict__ bd,
    const float* __restrict__ b1, const float* __restrict__ Wo,
    const float* __restrict__ bl, const float* __restrict__ br, const float* __restrict__ bp,
    const float* __restrict__ bpr,
    unsigned short* __restrict__ WgT, unsigned short* __restrict__ WprojT,
    unsigned short* __restrict__ updT, unsigned short* __restrict__ ubf0,
    float* __restrict__ updatef, float* __restrict__ ss0,
    unsigned short* __restrict__ W1T, unsigned short* __restrict__ Pb,
    float* __restrict__ b1p, float* __restrict__ wop, float* __restrict__ bproj)
{
    __shared__ float tile[32][33];
    int b = blockIdx.x, tid = threadIdx.x;
    if (b < 3040) {
        // transpose section
        const float* in; unsigned short* out; int R, C, ldo, rb, cb;
        if (b < 2048)      { in = Wg; out = WgT; R = 2048; C = 1024; ldo = 2048; rb = (b & 63) * 32; cb = (b >> 6) * 32; }
        else if (b < 2208) { int t = b - 2048; in = Wl; out = WprojT;            R = 1024; C = 150; ldo = 1024; rb = (t & 31) * 32; cb = (t >> 5) * 32; }
        else if (b < 2368) { int t = b - 2208; in = Wr; out = WprojT + 192*1024; R = 1024; C = 150; ldo = 1024; rb = (t & 31) * 32; cb = (t >> 5) * 32; }
        else if (b < 2528) { int t = b - 2368; in = Wp; out = WprojT + 384*1024; R = 1024; C = 150; ldo = 1024; rb = (t & 31) * 32; cb = (t >> 5) * 32; }
        else               { int t = b - 2528; in = span_vecs; out = updT;       R = 512;  C = 1024; ldo = 512;  rb = (t & 15) * 32; cb = (t >> 4) * 32; }
        int tx = tid & 31, ty = tid >> 5;
#pragma unroll
        for (int k = 0; k < 4; ++k) {
            int r = rb + ty + k*8, c = cb + tx;
            if (r < R && c < C) tile[ty + k*8][tx] = in[(size_t)r*C + c];
        }
        __syncthreads();
#pragma unroll
        for (int k = 0; k < 4; ++k) {
            int c = cb + ty + k*8, r = rb + tx;
            if (r < R && c < C) out[(size_t)c*ldo + r] = f2bf(tile[tx][ty + k*8]);
        }
        return;
    }
    // misc init: grid-stride over 512 blocks
    int g = (b - 3040) * 256 + tid;
    const int gsz = 512 * 256;
    for (int i = g; i < 512*1024; i += gsz) {
        float v = span_vecs[i];
        updatef[i] = v;
        ubf0[(i >> 10)*2048 + (i & 1023)] = f2bf(v);
    }
    for (int i = g; i < 512; i += gsz) ss0[i] = span_scores[i];
    for (int i = g; i < 160*168; i += gsz) {
        int n = i / 168, k = i % 168;
        W1T[i] = f2bf((n < 150 && k < 150) ? W1g[k*150 + n] : 0.f);
    }
    for (int i = g; i < 10*168; i += gsz) {
        int bk = i / 168, h = i % 168;
        float v = 0.f;
        if (h < 150) {
            v = bd[h];
            for (int e = 0; e < 20; ++e) v += Edist[bk*20 + e] * Wd[e*150 + h];
        }
        Pb[i] = f2bf(v);
    }
    for (int i = g; i < 160; i += gsz) {
        b1p[i] = (i < 150) ? b1[i] : 0.f;
        wop[i] = (i < 150) ? Wo[i] : 0.f;
    }
    for (int i = g; i < 640; i += gsz) {
        float v = 0.f;
        if (i < 150) v = bl[i];
        else if (i >= 192 && i < 342) v = br[i - 192];
        else if (i >= 384 && i < 534) v = bp[i - 384];
        else if (i == 576) v = bpr[0];
        bproj[i] = v;
    }
    // WprojT zero pads + Wpr row
    for (int i = g; i < 42*1024; i += gsz) { WprojT[150*1024 + i] = 0; WprojT[342*1024 + i] = 0; WprojT[534*1024 + i] = 0; }
    for (int i = g; i < 1024; i += gsz) WprojT[576*1024 + i] = f2bf(Wpr[i]);
    for (int i = g; i < 63*1024; i += gsz) WprojT[577*1024 + i] = 0;
}

// ---------------- generic 64x64 bf16 MFMA GEMM, register-prefetch pipelined ----------------
// C[m][n] = sum_k A[m][k] * BT[n][k]
// mode 0: Cb = bf16(acc+bias); if n==576 also ss1[m] = fp32    (projections -> lrsb)
// mode 1: Cf = acc; Cb = bf16(acc)                              (ctxt)
// mode 2: g = sigmoid(acc+bias); nu = g*uf+(1-g)*cf; uout, Cb, updT (gate)
__global__ __launch_bounds__(256) void k_gemm64(
    const unsigned short* __restrict__ A, int lda,
    const unsigned short* __restrict__ BT, int ldb,
    int K, const float* __restrict__ bias,
    float* __restrict__ Cf, int ldc,
    unsigned short* __restrict__ Cb, int ldcb,
    const float* __restrict__ uf, const float* __restrict__ cf,
    float* __restrict__ uout, unsigned short* __restrict__ updTout,
    float* __restrict__ ss1, int mode)
{
    __shared__ __align__(16) unsigned short As[64*72];
    __shared__ __align__(16) unsigned short Bs[64*72];
    int tid = threadIdx.x;
    int lane = tid & 63, w = tid >> 6;
    int wy = w >> 1, wx = w & 1;
    int ln15 = lane & 15, kg = lane >> 4;
    int m0 = blockIdx.x * 64, n0 = blockIdx.y * 64;
    int r0 = tid >> 3, c8 = (tid & 7) * 8;
    const unsigned short* pA0 = A + (size_t)(m0 + r0)*lda + c8;
    const unsigned short* pA1 = pA0 + (size_t)32*lda;
    const unsigned short* pB0 = BT + (size_t)(n0 + r0)*ldb + c8;
    const unsigned short* pB1 = pB0 + (size_t)32*ldb;
    floatx4 acc[2][2] = {};
    uint4 va0 = *(const uint4*)pA0, va1 = *(const uint4*)pA1;
    uint4 vb0 = *(const uint4*)pB0, vb1 = *(const uint4*)pB1;
    for (int kb = 0; kb < K; kb += 64) {
        __syncthreads();                      // previous iter's readers done
        *(uint4*)(&As[r0*72 + c8])        = va0;
        *(uint4*)(&As[(r0 + 32)*72 + c8]) = va1;
        *(uint4*)(&Bs[r0*72 + c8])        = vb0;
        *(uint4*)(&Bs[(r0 + 32)*72 + c8]) = vb1;
        __syncthreads();
        int kn = kb + 64;
        if (kn < K) {                         // prefetch next tile while computing
            va0 = *(const uint4*)(pA0 + kn); va1 = *(const uint4*)(pA1 + kn);
            vb0 = *(const uint4*)(pB0 + kn); vb1 = *(const uint4*)(pB1 + kn);
        }
#pragma unroll
        for (int ks = 0; ks < 2; ++ks) {
            int ko = ks*32 + kg*8;
            short8 a0 = *(const short8*)(&As[(wy*32 + ln15)*72 + ko]);
            short8 a1 = *(const short8*)(&As[(wy*32 + 16 + ln15)*72 + ko]);
            short8 b0 = *(const short8*)(&Bs[(wx*32 + ln15)*72 + ko]);
            short8 b1 = *(const short8*)(&Bs[(wx*32 + 16 + ln15)*72 + ko]);
            acc[0][0] = MFMA_BF16(a0, b0, acc[0][0]);
            acc[0][1] = MFMA_BF16(a0, b1, acc[0][1]);
            acc[1][0] = MFMA_BF16(a1, b0, acc[1][0]);
            acc[1][1] = MFMA_BF16(a1, b1, acc[1][1]);
        }
    }
#pragma unroll
    for (int mt = 0; mt < 2; ++mt)
#pragma unroll
    for (int nt = 0; nt < 2; ++nt) {
        int n  = n0 + wx*32 + nt*16 + ln15;
        int mb = m0 + wy*32 + mt*16 + kg*4;
        if (mode == 0) {
            float b_ = bias[n];
#pragma unroll
            for (int rg = 0; rg < 4; ++rg) {
                float v = acc[mt][nt][rg] + b_;
                Cb[(size_t)(mb + rg)*ldcb + n] = f2bf(v);
                if (n == 576) ss1[mb + rg] = v;
            }
        } else if (mode == 1) {
#pragma unroll
            for (int rg = 0; rg < 4; ++rg) {
                float v = acc[mt][nt][rg];
                Cf[(size_t)(mb + rg)*ldc + n] = v;
                Cb[(size_t)(mb + rg)*ldcb + n] = f2bf(v);
            }
        } else {
            float b_ = bias[n];
            ushort4 tv;
            unsigned short* tvp = &tv.x;
#pragma unroll
            for (int rg = 0; rg < 4; ++rg) {
                float v = acc[mt][nt][rg] + b_;
                float gg = 1.f / (1.f + __expf(-v));
                size_t off = (size_t)(mb + rg)*1024 + n;
                float nu = gg*uf[off] + (1.f - gg)*cf[off];
                uout[off] = nu;
                unsigned short nb = f2bf(nu);
                Cb[(size_t)(mb + rg)*ldcb + n] = nb;
                tvp[rg] = nb;
            }
            *(ushort4*)(updTout + (size_t)n*512 + mb) = tv;
        }
    }
}

// ---------------- row softmax (masked j<=i) -> bf16 probs ----------------
__global__ __launch_bounds__(256) void k_softmax(const float* __restrict__ scores,
                                                 unsigned short* __restrict__ probsb)
{
    int i = blockIdx.x;
    int tid = threadIdx.x;
    int lane = tid & 63, w = tid >> 6;
    __shared__ float red[8];
    int j0 = tid, j1 = tid + 256;
    bool v0 = (j0 <= i), v1 = (j1 <= i);
    float x0 = v0 ? scores[(size_t)i*512 + j0] : -1e30f;
    float x1 = v1 ? scores[(size_t)i*512 + j1] : -1e30f;
    float mx = fmaxf(x0, x1);
    for (int off = 32; off; off >>= 1) mx = fmaxf(mx, __shfl_xor(mx, off));
    if (lane == 0) red[w] = mx;
    __syncthreads();
    mx = fmaxf(fmaxf(red[0], red[1]), fmaxf(red[2], red[3]));
    float p0 = v0 ? __expf(x0 - mx) : 0.f;
    float p1 = v1 ? __expf(x1 - mx) : 0.f;
    float sm = p0 + p1;
    for (int off = 32; off; off >>= 1) sm += __shfl_xor(sm, off);
    if (lane == 0) red[4 + w] = sm;
    __syncthreads();
    float inv = 1.f / (red[4] + red[5] + red[6] + red[7]);
    probsb[(size_t)i*512 + j0] = f2bf(p0 * inv);
    probsb[(size_t)i*512 + j1] = f2bf(p1 * inv);
}

// ---------------- pair kernel: h -> h@W1 -> relu -> .Wo -> scores (B from global, 1 barrier) ----
__global__ __launch_bounds__(512, 2) void k_pair(
    const unsigned short* __restrict__ lrsb,   // [512][640] bf16: l|pad|r|pad|s|pad|ss|pad
    const unsigned short* __restrict__ Pb,     // [10][168]
    const unsigned short* __restrict__ W1Tg,   // [160][168]
    const float* __restrict__ b1p, const float* __restrict__ wop,
    const float* __restrict__ bo,
    const float* __restrict__ ssbuf,
    const int* __restrict__ beginp, const int* __restrict__ endp,
    float* __restrict__ scoresOut)
{
    __shared__ __align__(16) unsigned short smR[74*168]; // l_i(16) s_i(16) r_j(16) s_j(16) P(10)
    int tid = threadIdx.x;
    int i0 = blockIdx.x * 16, j0 = blockIdx.y * 16;
    for (int c = tid; c < 74*21; c += 512) {
        int row = c / 21, c8 = (c % 21) * 8;
        const unsigned short* src;
        if (row < 16)      src = lrsb + (size_t)(i0 + row)*640 + c8;            // l_i
        else if (row < 32) src = lrsb + (size_t)(i0 + row - 16)*640 + 384 + c8; // s_i
        else if (row < 48) src = lrsb + (size_t)(j0 + row - 32)*640 + 192 + c8; // r_j
        else if (row < 64) src = lrsb + (size_t)(j0 + row - 48)*640 + 384 + c8; // s_j
        else               src = Pb + (size_t)(row - 64)*168 + c8;              // P
        *(uint4*)(&smR[row*168 + c8]) = *(const uint4*)src;
    }
    int lane = tid & 63, w = tid >> 6;
    int ln15 = lane & 15, kg = lane >> 4;
    int iw = i0 + 2*w;
    int ej = endp[j0 + ln15];
    int da = bucketd(beginp[iw] - ej);
    int db = bucketd(beginp[iw + 1] - ej);
    __syncthreads();
    floatx4 acc[2][10] = {};
    for (int kb = 0; kb < 5; ++kb) {
        int ko = kb*32 + kg*8;
        short8 bv[10];
#pragma unroll
        for (int nt = 0; nt < 10; ++nt)
            bv[nt] = *(const short8*)(W1Tg + (size_t)(nt*16 + ln15)*168 + ko);
        short8 rv  = *(const short8*)(&smR[(32 + ln15)*168 + ko]);
        short8 sjv = *(const short8*)(&smR[(48 + ln15)*168 + ko]);
        short8 hf[2];
#pragma unroll
        for (int mt = 0; mt < 2; ++mt) {
            int ri = 2*w + mt;
            short8 lv  = *(const short8*)(&smR[ri*168 + ko]);
            short8 siv = *(const short8*)(&smR[(16 + ri)*168 + ko]);
            int d = mt ? db : da;
            short8 pv  = *(const short8*)(&smR[(64 + d)*168 + ko]);
#pragma unroll
            for (int t = 0; t < 8; ++t) {
                float h = bf2f(lv[t]) + bf2f(rv[t]) + bf2f(siv[t]) * bf2f(sjv[t]) + bf2f(pv[t]);
                h = fmaxf(h, 0.f);
                hf[mt][t] = (short)f2bf(h);
            }
        }
#pragma unroll
        for (int nt = 0; nt < 10; ++nt) {
            acc[0][nt] = MFMA_BF16(hf[0], bv[nt], acc[0][nt]);
            acc[1][nt] = MFMA_BF16(hf[1], bv[nt], acc[1][nt]);
        }
    }
    float part[2][4] = {};
#pragma unroll
    for (int nt = 0; nt < 10; ++nt) {
        int n = nt*16 + ln15;
        float b1v = b1p[n], wv = wop[n];
#pragma unroll
        for (int mt = 0; mt < 2; ++mt)
#pragma unroll
            for (int rg = 0; rg < 4; ++rg)
                part[mt][rg] += fmaxf(acc[mt][nt][rg] + b1v, 0.f) * wv;
    }
    float bo0 = bo[0];
#pragma unroll
    for (int mt = 0; mt < 2; ++mt) {
#pragma unroll
        for (int rg = 0; rg < 4; ++rg) {
            float p = part[mt][rg];
            p += __shfl_xor(p, 1); p += __shfl_xor(p, 2);
            p += __shfl_xor(p, 4); p += __shfl_xor(p, 8);
            part[mt][rg] = p;
        }
        if (ln15 == 0) {
            int i = iw + mt;
            float ssi = ssbuf[i];
            int jb = j0 + kg*4;
            float r0 = part[mt][0] + bo0 + ssi + ssbuf[jb + 0]; if (i == jb + 0) r0 = 0.f;
            float r1 = part[mt][1] + bo0 + ssi + ssbuf[jb + 1]; if (i == jb + 1) r1 = 0.f;
            float r2 = part[mt][2] + bo0 + ssi + ssbuf[jb + 2]; if (i == jb + 2) r2 = 0.f;
            float r3 = part[mt][3] + bo0 + ssi + ssbuf[jb + 3]; if (i == jb + 3) r3 = 0.f;
            float4 vv; vv.x = r0; vv.y = r1; vv.z = r2; vv.w = r3;
            *(float4*)(scoresOut + (size_t)i*512 + jb) = vv;
        }
    }
}

// ---------------- finalize: copy + overwrite merged (binary search over sorted prune) --------
__global__ __launch_bounds__(256) void k_final(const float* __restrict__ allv,
                                               const int* __restrict__ prune,
                                               const int* __restrict__ lengths,
                                               const float* __restrict__ updatef,
                                               float* __restrict__ out)
{
    int row = blockIdx.x;
    if (row < 30720) {
        int len = lengths[0];
        if (len > 512) len = 512;
        int lo = 0, hi = len;
        while (lo < hi) { int mid = (lo + hi) >> 1; if (prune[mid] < row) lo = mid + 1; else hi = mid; }
        bool found = (lo < len) && (prune[lo] == row);
        const float4* src = found ? (const float4*)(updatef + (size_t)lo*1024)
                                  : (const float4*)(allv + (size_t)row*1024);
        ((float4*)(out + (size_t)row*1024))[threadIdx.x] = src[threadIdx.x];
    } else {
        int k = row - 30720;   // update output section
        ((float4*)(out + (size_t)row*1024))[threadIdx.x] =
            ((const float4*)(updatef + (size_t)k*1024))[threadIdx.x];
    }
}

// ---------------- host ----------------
extern "C" void kernel_launch(void* const* d_in, const int* in_sizes, int n_in,
                              void* d_out, int out_size, void* d_ws, size_t ws_size,
                              hipStream_t stream) {
    const float* all_span    = (const float*)d_in[0];
    const float* span_vecs   = (const float*)d_in[1];
    const float* span_scores = (const float*)d_in[2];
    const int*   beginp      = (const int*)d_in[4];
    const int*   endp        = (const int*)d_in[5];
    const int*   prune       = (const int*)d_in[6];
    const int*   lengths     = (const int*)d_in[7];
    const float* Wl = (const float*)d_in[8];  const float* bl = (const float*)d_in[9];
    const float* Wr = (const float*)d_in[10]; const float* br = (const float*)d_in[11];
    const float* Wp = (const float*)d_in[12]; const float* bp = (const float*)d_in[13];
    const float* Edist = (const float*)d_in[14];
    const float* Wd = (const float*)d_in[15]; const float* bd = (const float*)d_in[16];
    const float* W1 = (const float*)d_in[17]; const float* b1 = (const float*)d_in[18];
    const float* Wo = (const float*)d_in[19]; const float* bo = (const float*)d_in[20];
    const float* Wg = (const float*)d_in[21]; const float* bg = (const float*)d_in[22];
    const float* Wpr = (const float*)d_in[23]; const float* bpr = (const float*)d_in[24];

    char* wsb = (char*)d_ws;
    size_t o = 0;
    auto nxt = [&](size_t b) { size_t r = o; o += (b + 255) & ~(size_t)255; return r; };
    float* updatef  = (float*)(wsb + nxt(512*1024*4));
    float* ctxtf    = (float*)(wsb + nxt(512*1024*4));
    float* scoresws = (float*)(wsb + nxt(512*512*4));
    float* ss0      = (float*)(wsb + nxt(512*4));
    float* ss1      = (float*)(wsb + nxt(512*4));
    float* bproj    = (float*)(wsb + nxt(640*4));
    float* b1p      = (float*)(wsb + nxt(160*4));
    float* wop      = (float*)(wsb + nxt(160*4));
    unsigned short* ubf0    = (unsigned short*)(wsb + nxt(512*2048*2));
    unsigned short* ubf1    = (unsigned short*)(wsb + nxt(512*2048*2));
    unsigned short* updT    = (unsigned short*)(wsb + nxt(1024*512*2));
    unsigned short* probsb  = (unsigned short*)(wsb + nxt(512*512*2));
    unsigned short* lrsb    = (unsigned short*)(wsb + nxt(512*640*2));
    unsigned short* WgT     = (unsigned short*)(wsb + nxt(1024*2048*2));
    unsigned short* WprojT  = (unsigned short*)(wsb + nxt(640*1024*2));
    unsigned short* W1T     = (unsigned short*)(wsb + nxt(160*168*2));
    unsigned short* Pb      = (unsigned short*)(wsb + nxt(10*168*2));

    float* outp = (float*)d_out;
    float* out_scores = outp + 31457280 + 524288;

    k_prep<<<3552, 256, 0, stream>>>(Wg, Wl, Wr, Wp, Wpr, span_vecs, span_scores,
                                     W1, Edist, Wd, bd, b1, Wo, bl, br, bp, bpr,
                                     WgT, WprojT, updT, ubf0, updatef, ss0,
                                     W1T, Pb, b1p, wop, bproj);

    // call 0: projections (+fused pruner col, unused), pair with span_scores
    k_gemm64<<<dim3(8, 10), 256, 0, stream>>>(ubf0, 2048, WprojT, 1024, 1024, bproj,
                                              nullptr, 0, lrsb, 640,
                                              nullptr, nullptr, nullptr, nullptr, ss1, 0);
    k_pair<<<dim3(32, 32), 512, 0, stream>>>(lrsb, Pb, W1T, b1p, wop, bo, ss0, beginp, endp, scoresws);

    unsigned short* ucur = ubf0;
    unsigned short* unxt = ubf1;
    for (int it = 0; it < 2; ++it) {
        k_softmax<<<512, 256, 0, stream>>>(scoresws, probsb);
        // ctxt = probs @ update   (BT = updT from prep / previous gate)
        k_gemm64<<<dim3(8, 16), 256, 0, stream>>>(probsb, 512, updT, 512, 512, nullptr,
                                                  ctxtf, 1024, ucur + 1024, 2048,
                                                  nullptr, nullptr, nullptr, nullptr, nullptr, 1);
        // gate: writes updatef (fp32), unxt (bf16 rows), updT (bf16 transposed)
        k_gemm64<<<dim3(8, 16), 256, 0, stream>>>(ucur, 2048, WgT, 2048, 2048, bg,
                                                  nullptr, 0, unxt, 2048,
                                                  updatef, ctxtf, updatef, updT, nullptr, 2);
        // projections of new update (+fused pruner -> ss1)
        k_gemm64<<<dim3(8, 10), 256, 0, stream>>>(unxt, 2048, WprojT, 1024, 1024, bproj,
                                                  nullptr, 0, lrsb, 640,
                                                  nullptr, nullptr, nullptr, nullptr, ss1, 0);
        float* sdst = (it == 1) ? out_scores : scoresws;
        k_pair<<<dim3(32, 32), 512, 0, stream>>>(lrsb, Pb, W1T, b1p, wop, bo, ss1, beginp, endp, sdst);
        unsigned short* t = ucur; ucur = unxt; unxt = t;
    }

    k_final<<<31232, 256, 0, stream>>>(all_span, prune, lengths, updatef, outp);
}